// Round 6
// baseline (299.688 us; speedup 1.0000x reference)
//
#include <hip/hip_runtime.h>

#define NEXP 8
#define NTOK 1024
#define HID 2048
#define ITR 1024

typedef __attribute__((ext_vector_type(8))) short short8;
typedef __attribute__((ext_vector_type(4))) short short4v;
typedef __attribute__((ext_vector_type(4))) float f32x4;
typedef __attribute__((ext_vector_type(2))) float f32x2;
typedef __attribute__((ext_vector_type(2))) unsigned uint2v;

__device__ __forceinline__ unsigned short f2bf(float f) {
  unsigned u = __float_as_uint(f);
  u += 0x7fffu + ((u >> 16) & 1u);
  return (unsigned short)(u >> 16);
}

__device__ __forceinline__ void gl_lds16(const void* g, void* l) {
  __builtin_amdgcn_global_load_lds(
      (const __attribute__((address_space(1))) unsigned int*)g,
      (__attribute__((address_space(3))) unsigned int*)l, 16, 0, 0);
}

// counted waits: leave newest N VMEM in flight across barriers (T4)
#define VMCNT8                                           \
  do {                                                   \
    asm volatile("s_waitcnt vmcnt(8)" ::: "memory");     \
    __builtin_amdgcn_sched_barrier(0);                   \
  } while (0)
#define LGKM0                                            \
  do {                                                   \
    asm volatile("s_waitcnt lgkmcnt(0)" ::: "memory");   \
    __builtin_amdgcn_sched_barrier(0);                   \
  } while (0)
#define BARRIER                                          \
  do {                                                   \
    __builtin_amdgcn_s_barrier();                        \
    __builtin_amdgcn_sched_barrier(0);                   \
  } while (0)

// ---------------- setup: zero out + x fp32->bf16 ----------------
__global__ __launch_bounds__(256) void k_setup(const float* __restrict__ x,
                                               unsigned int* __restrict__ xb,
                                               float* __restrict__ out) {
  int i = blockIdx.x * 256 + threadIdx.x;  // 524288 threads, 4 f32 each
  f32x4 z = {0.f, 0.f, 0.f, 0.f};
  *(f32x4*)(out + (size_t)i * 4) = z;
  f32x4 v = *(const f32x4*)(x + (size_t)i * 4);
  xb[(size_t)i * 2] = (unsigned)f2bf(v[0]) | ((unsigned)f2bf(v[1]) << 16);
  xb[(size_t)i * 2 + 1] = (unsigned)f2bf(v[2]) | ((unsigned)f2bf(v[3]) << 16);
}

// ---------------- router: top-2, flat compacted lists ----------------
__global__ __launch_bounds__(1024) void k_router(const float* __restrict__ rp,
                                                 int* __restrict__ counts,
                                                 int* __restrict__ base,
                                                 int* __restrict__ toklist,
                                                 float* __restrict__ wlist) {
  __shared__ int c[NEXP];
  __shared__ int sb[NEXP];
  int n = threadIdx.x;
  if (n < NEXP) c[n] = 0;
  __syncthreads();
  float r[NEXP];
#pragma unroll
  for (int e = 0; e < NEXP; ++e) r[e] = rp[n * NEXP + e];
  int i1 = 0;
  float m1 = r[0];
#pragma unroll
  for (int e = 1; e < NEXP; ++e)
    if (r[e] > m1) { m1 = r[e]; i1 = e; }
  int i2 = -1;
  float m2 = -3.4e38f;
#pragma unroll
  for (int e = 0; e < NEXP; ++e)
    if (e != i1 && r[e] > m2) { m2 = r[e]; i2 = e; }
  float p1 = 1.f / (1.f + __expf(m2 - m1));
  float p2 = 1.f - p1;
  int s1 = atomicAdd(&c[i1], 1);
  int s2 = atomicAdd(&c[i2], 1);
  __syncthreads();
  if (n == 0) {
    int a = 0;
#pragma unroll
    for (int e = 0; e < NEXP; ++e) { sb[e] = a; a += c[e]; }
  }
  __syncthreads();
  int q1 = sb[i1] + s1;
  toklist[q1] = n; wlist[q1] = p1;
  int q2 = sb[i2] + s2;
  toklist[q2] = n; wlist[q2] = p2;
  if (n < NEXP) { counts[n] = c[n]; base[n] = sb[n]; }
}

// ===== grouped GEMM fc1/fc3 + swiglu, fused fp32->bf16 W convert =====
// BM=256 BN=32 BK=64, 512 thr, XCD-pinned, dbuf, counted-vmcnt pipeline.
__global__ __launch_bounds__(512, 4) void k_gemm13(
    const float* __restrict__ fc1, const float* __restrict__ fc3,
    const unsigned short* __restrict__ xb, const int* __restrict__ counts,
    const int* __restrict__ base, const int* __restrict__ toklist,
    unsigned short* __restrict__ act) {
  const int bid = blockIdx.x;  // 1024 blocks, e = bid&7 -> XCD pin
  const int e = bid & 7;
  const int t2 = bid >> 3;
  const int ntile = t2 & 31;   // 32 n-tiles of 32
  const int mtile = t2 >> 5;   // 0..3
  const int cnt = counts[e];
  const int mbase = mtile * 256;
  if (mbase >= cnt) return;
  const int n0t = ntile * 32;
  const int rbase = base[e];

  __shared__ __align__(16) unsigned short lds[2 * 20480];
  const int tid = threadIdx.x;
  const int lane = tid & 63, w = tid >> 6;

  // ---- A staging: 4x16B chunks/thread, source pre-XOR-swizzled ----
  const unsigned short* srcA[4];
  int dofA[4];
#pragma unroll
  for (int i = 0; i < 4; ++i) {
    int cc = i * 512 + tid;
    int r = cc >> 3, b = cc & 7;
    int row = mbase + r;
    int tok = toklist[rbase + ((row < cnt) ? row : (cnt - 1))];
    srcA[i] = xb + (size_t)tok * HID + (b ^ (r & 7)) * 8;
    dofA[i] = (i * 512 + w * 64) * 8;  // ushort, wave-uniform
  }

  // ---- W staging (reg -> cvt -> swizzled ds_write) ----
  const int mat = tid >> 8;  // 0: fc1, 1: fc3
  const int c8 = tid & 255;
  const int kq = c8 >> 4;         // 0..15, k4 = kq*4
  const int n0 = (c8 & 15) * 2;   // 0..30 even
  const float* wsrc = (mat ? fc3 : fc1) + (size_t)e * HID * ITR +
                      (size_t)(kq * 4) * ITR + n0t + n0;
  int wrb[2];
#pragma unroll
  for (int t = 0; t < 2; ++t) {
    int nn = n0 + t;
    wrb[t] = 32768 + mat * 4096 + nn * 128 + ((kq ^ (nn & 15)) << 3);
  }

  // ---- fragment byte offsets ----
  int offA[2][2], woff[2][2][2];
#pragma unroll
  for (int mi = 0; mi < 2; ++mi)
#pragma unroll
    for (int s = 0; s < 2; ++s) {
      int kb = s * 4 + (lane >> 4);
      int rowA = w * 32 + mi * 16 + (lane & 15);
      offA[mi][s] = rowA * 128 + ((kb ^ (rowA & 7)) << 4);
    }
#pragma unroll
  for (int ni = 0; ni < 2; ++ni)
#pragma unroll
    for (int s = 0; s < 2; ++s) {
      int n = ni * 16 + (lane & 15);
      int kb0 = s * 8 + (lane >> 4) * 2;
      woff[ni][s][0] = n * 128 + ((kb0 ^ (n & 15)) << 3);
      woff[ni][s][1] = n * 128 + (((kb0 + 1) ^ (n & 15)) << 3);
    }

  f32x4 acc1[2][2], acc3[2][2];
#pragma unroll
  for (int mi = 0; mi < 2; ++mi)
#pragma unroll
    for (int ni = 0; ni < 2; ++ni) {
      acc1[mi][ni] = (f32x4){0.f, 0.f, 0.f, 0.f};
      acc3[mi][ni] = (f32x4){0.f, 0.f, 0.f, 0.f};
    }

  float wvA[8], wvB[8];

#define STGA13(bb, kt)                                    \
  {                                                       \
    int k0 = (kt) * 64;                                   \
    unsigned short* Lb = lds + (bb) * 20480;              \
    _Pragma("unroll") for (int i = 0; i < 4; ++i)         \
        gl_lds16(srcA[i] + k0, Lb + dofA[i]);             \
  }
#define LOADW13(wv, kt)                                   \
  {                                                       \
    const float* g = wsrc + (size_t)(kt) * 64 * ITR;      \
    _Pragma("unroll") for (int j = 0; j < 4; ++j) {       \
      f32x2 vv = *(const f32x2*)(g + (size_t)j * ITR);    \
      wv[2 * j] = vv[0];                                  \
      wv[2 * j + 1] = vv[1];                              \
    }                                                     \
  }
#define CVTW13(wv, bb)                                                        \
  {                                                                           \
    _Pragma("unroll") for (int t = 0; t < 2; ++t) {                           \
      unsigned lo = (unsigned)f2bf(wv[t]) | ((unsigned)f2bf(wv[2 + t]) << 16);\
      unsigned hi =                                                           \
          (unsigned)f2bf(wv[4 + t]) | ((unsigned)f2bf(wv[6 + t]) << 16);      \
      uint2v v = {lo, hi};                                                    \
      *(uint2v*)((char*)lds + (bb) * 40960 + wrb[t]) = v;                     \
    }                                                                         \
  }
#define COMPUTE13(bb)                                                         \
  {                                                                           \
    const char* Lb = (const char*)lds + (bb) * 40960;                         \
    _Pragma("unroll") for (int s = 0; s < 2; ++s) {                           \
      short8 af[2];                                                           \
      _Pragma("unroll") for (int mi = 0; mi < 2; ++mi)                        \
          af[mi] = *(const short8*)(Lb + offA[mi][s]);                        \
      _Pragma("unroll") for (int ni = 0; ni < 2; ++ni) {                      \
        short4v l1 = *(const short4v*)(Lb + 32768 + woff[ni][s][0]);          \
        short4v h1 = *(const short4v*)(Lb + 32768 + woff[ni][s][1]);          \
        short4v l3 = *(const short4v*)(Lb + 36864 + woff[ni][s][0]);          \
        short4v h3 = *(const short4v*)(Lb + 36864 + woff[ni][s][1]);          \
        short8 w1f = __builtin_shufflevector(l1, h1, 0, 1, 2, 3, 4, 5, 6, 7); \
        short8 w3f = __builtin_shufflevector(l3, h3, 0, 1, 2, 3, 4, 5, 6, 7); \
        _Pragma("unroll") for (int mi = 0; mi < 2; ++mi) {                    \
          acc1[mi][ni] = __builtin_amdgcn_mfma_f32_16x16x32_bf16(             \
              af[mi], w1f, acc1[mi][ni], 0, 0, 0);                            \
          acc3[mi][ni] = __builtin_amdgcn_mfma_f32_16x16x32_bf16(             \
              af[mi], w3f, acc3[mi][ni], 0, 0, 0);                            \
        }                                                                     \
      }                                                                       \
    }                                                                         \
  }

  // prologue: W0,W1 regs + A0 staged; drain W0 only; W0 -> LDS buf0
  LOADW13(wvA, 0);
  LOADW13(wvB, 1);
  STGA13(0, 0);
  VMCNT8;           // outstanding: W1(4)+A0(4); W0 drained
  CVTW13(wvA, 0);
  LGKM0;
  BARRIER;

  for (int kt = 0; kt < 32; kt += 2) {
    // --- step A: compute kt on buf0; stage kt+1 -> buf1 ---
    {
      int kw = kt + 2 < 32 ? kt + 2 : 31;
      int ka = kt + 1 < 32 ? kt + 1 : 31;
      LOADW13(wvA, kw);   // 4 VMEM
      STGA13(1, ka);      // 4 VMEM
      VMCNT8;             // drains A(kt) + W(kt+1)
      CVTW13(wvB, 1);     // W(kt+1) -> buf1
      LGKM0;
      BARRIER;
      COMPUTE13(0);
      BARRIER;
    }
    // --- step B: compute kt+1 on buf1; stage kt+2 -> buf0 ---
    {
      int kw = kt + 3 < 32 ? kt + 3 : 31;
      int ka = kt + 2 < 32 ? kt + 2 : 31;
      LOADW13(wvB, kw);
      STGA13(0, ka);
      VMCNT8;             // drains A(kt+1) + W(kt+2)
      CVTW13(wvA, 0);     // W(kt+2) -> buf0
      LGKM0;
      BARRIER;
      COMPUTE13(1);
      BARRIER;
    }
  }

  // epilogue: swiglu -> LDS repack [256][40] -> coalesced 16B stores
  unsigned short* lact = lds;
#pragma unroll
  for (int mi = 0; mi < 2; ++mi)
#pragma unroll
    for (int ni = 0; ni < 2; ++ni)
#pragma unroll
      for (int rr = 0; rr < 4; ++rr) {
        float h1 = acc1[mi][ni][rr], h3 = acc3[mi][ni][rr];
        float a = h1 * (1.f / (1.f + __expf(-h1))) * h3;
        int row = w * 32 + mi * 16 + (lane >> 4) * 4 + rr;
        int col = ni * 16 + (lane & 15);
        lact[row * 40 + col] = f2bf(a);
      }
  __syncthreads();
#pragma unroll
  for (int p = 0; p < 2; ++p) {
    int row = p * 128 + (tid >> 2);
    int q = (tid & 3) * 8;
    if (mbase + row < cnt)
      *(short8*)(act + (size_t)(rbase + mbase + row) * ITR + n0t + q) =
          *(const short8*)&lact[row * 40 + q];
  }
}

// ===== grouped GEMM fc2 + scaled atomic combine, fused W convert =====
// BM=256 BN=32 BK=64, 512 thr, counted-vmcnt pipeline.
__global__ __launch_bounds__(512, 4) void k_gemm2(
    const float* __restrict__ fc2, const unsigned short* __restrict__ act,
    const int* __restrict__ counts, const int* __restrict__ base,
    const int* __restrict__ toklist, const float* __restrict__ wlist,
    float* __restrict__ out) {
  const int bid = blockIdx.x;  // 2048 blocks, e = bid&7 -> XCD pin
  const int e = bid & 7;
  const int t2 = bid >> 3;
  const int ntile = t2 & 63;   // 64 n-tiles of 32
  const int mtile = t2 >> 6;   // 0..3
  const int cnt = counts[e];
  const int mbase = mtile * 256;
  if (mbase >= cnt) return;
  const int n0t = ntile * 32;
  const int rbase = base[e];

  __shared__ __align__(16) unsigned short lds[2 * 18432];
  const int tid = threadIdx.x;
  const int lane = tid & 63, w = tid >> 6;

  const unsigned short* srcA[4];
  int dofA[4];
#pragma unroll
  for (int i = 0; i < 4; ++i) {
    int cc = i * 512 + tid;
    int r = cc >> 3, b = cc & 7;
    int arow = rbase + mbase + r;
    if (arow > 2047) arow = 2047;
    srcA[i] = act + (size_t)arow * ITR + (b ^ (r & 7)) * 8;
    dofA[i] = (i * 512 + w * 64) * 8;
  }

  // W staging: thread covers (k4..k4+3) x (n0); 512 threads = 64k x 32n
  const int kq = tid >> 5;   // 0..15
  const int n0 = tid & 31;   // 0..31
  const float* wsrc =
      fc2 + (size_t)e * ITR * HID + (size_t)(kq * 4) * HID + n0t + n0;
  const int wrb = 32768 + n0 * 128 + ((kq ^ (n0 & 15)) << 3);

  int offA[2][2], woff[2][2][2];
#pragma unroll
  for (int mi = 0; mi < 2; ++mi)
#pragma unroll
    for (int s = 0; s < 2; ++s) {
      int kb = s * 4 + (lane >> 4);
      int rowA = w * 32 + mi * 16 + (lane & 15);
      offA[mi][s] = rowA * 128 + ((kb ^ (rowA & 7)) << 4);
    }
#pragma unroll
  for (int ni = 0; ni < 2; ++ni)
#pragma unroll
    for (int s = 0; s < 2; ++s) {
      int n = ni * 16 + (lane & 15);
      int kb0 = s * 8 + (lane >> 4) * 2;
      woff[ni][s][0] = n * 128 + ((kb0 ^ (n & 15)) << 3);
      woff[ni][s][1] = n * 128 + (((kb0 + 1) ^ (n & 15)) << 3);
    }

  f32x4 acc[2][2];
#pragma unroll
  for (int mi = 0; mi < 2; ++mi)
#pragma unroll
    for (int ni = 0; ni < 2; ++ni) acc[mi][ni] = (f32x4){0.f, 0.f, 0.f, 0.f};

  float wvA[4], wvB[4];

#define STGA2(bb, kt)                                     \
  {                                                       \
    int k0 = (kt) * 64;                                   \
    unsigned short* Lb = lds + (bb) * 18432;              \
    _Pragma("unroll") for (int i = 0; i < 4; ++i)         \
        gl_lds16(srcA[i] + k0, Lb + dofA[i]);             \
  }
#define LOADW2(wv, kt)                                    \
  {                                                       \
    const float* g = wsrc + (size_t)(kt) * 64 * HID;      \
    _Pragma("unroll") for (int j = 0; j < 4; ++j)         \
        wv[j] = g[(size_t)j * HID];                       \
  }
#define CVTW2(wv, bb)                                                       \
  {                                                                         \
    unsigned lo = (unsigned)f2bf(wv[0]) | ((unsigned)f2bf(wv[1]) << 16);    \
    unsigned hi = (unsigned)f2bf(wv[2]) | ((unsigned)f2bf(wv[3]) << 16);    \
    uint2v v = {lo, hi};                                                    \
    *(uint2v*)((char*)lds + (bb) * 36864 + wrb) = v;                        \
  }
#define COMPUTE2(bb)                                                          \
  {                                                                           \
    const char* Lb = (const char*)lds + (bb) * 36864;                         \
    _Pragma("unroll") for (int s = 0; s < 2; ++s) {                           \
      short8 af[2];                                                           \
      _Pragma("unroll") for (int mi = 0; mi < 2; ++mi)                        \
          af[mi] = *(const short8*)(Lb + offA[mi][s]);                        \
      _Pragma("unroll") for (int ni = 0; ni < 2; ++ni) {                      \
        short4v lw = *(const short4v*)(Lb + 32768 + woff[ni][s][0]);          \
        short4v hw = *(const short4v*)(Lb + 32768 + woff[ni][s][1]);          \
        short8 wf = __builtin_shufflevector(lw, hw, 0, 1, 2, 3, 4, 5, 6, 7);  \
        _Pragma("unroll") for (int mi = 0; mi < 2; ++mi)                      \
            acc[mi][ni] = __builtin_amdgcn_mfma_f32_16x16x32_bf16(            \
                af[mi], wf, acc[mi][ni], 0, 0, 0);                            \
      }                                                                       \
    }                                                                         \
  }

  LOADW2(wvA, 0);
  LOADW2(wvB, 1);
  STGA2(0, 0);
  VMCNT8;           // outstanding: W1(4)+A0(4); W0 drained
  CVTW2(wvA, 0);
  LGKM0;
  BARRIER;

  for (int kt = 0; kt < 16; kt += 2) {
    {
      int kw = kt + 2 < 16 ? kt + 2 : 15;
      int ka = kt + 1 < 16 ? kt + 1 : 15;
      LOADW2(wvA, kw);
      STGA2(1, ka);
      VMCNT8;             // drains A(kt) + W(kt+1)
      CVTW2(wvB, 1);
      LGKM0;
      BARRIER;
      COMPUTE2(0);
      BARRIER;
    }
    {
      int kw = kt + 3 < 16 ? kt + 3 : 15;
      int ka = kt + 2 < 16 ? kt + 2 : 15;
      LOADW2(wvB, kw);
      STGA2(0, ka);
      VMCNT8;             // drains A(kt+1) + W(kt+2)
      CVTW2(wvA, 0);
      LGKM0;
      BARRIER;
      COMPUTE2(1);
      BARRIER;
    }
  }

  // epilogue: scale by routed prob, atomic combine (2 adds / out element)
#pragma unroll
  for (int mi = 0; mi < 2; ++mi)
#pragma unroll
    for (int rr = 0; rr < 4; ++rr) {
      int lr = w * 32 + mi * 16 + (lane >> 4) * 4 + rr;
      int grow = mbase + lr;
      if (grow < cnt) {
        float pv = wlist[rbase + grow];
        int tok = toklist[rbase + grow];
        float* orow = out + (size_t)tok * HID + n0t + (lane & 15);
#pragma unroll
        for (int ni = 0; ni < 2; ++ni)
          atomicAdd(orow + ni * 16, acc[mi][ni][rr] * pv);
      }
    }
}

extern "C" void kernel_launch(void* const* d_in, const int* in_sizes, int n_in,
                              void* d_out, int out_size, void* d_ws,
                              size_t ws_size, hipStream_t stream) {
  (void)in_sizes; (void)n_in; (void)out_size; (void)ws_size;
  const float* x = (const float*)d_in[0];
  const float* rp = (const float*)d_in[1];
  const float* fc1 = (const float*)d_in[2];
  const float* fc2 = (const float*)d_in[3];
  const float* fc3 = (const float*)d_in[4];
  float* out = (float*)d_out;
  char* ws = (char*)d_ws;

  int* counts = (int*)ws;                                // 32 B
  int* base = (int*)(ws + 256);                          // 32 B
  int* toklist = (int*)(ws + 4096);                      // 8 KB
  float* wlist = (float*)(ws + 12288);                   // 8 KB
  unsigned short* xb = (unsigned short*)(ws + 32768);    // 4 MB bf16 x
  unsigned short* act = (unsigned short*)(ws + 4227072); // 4 MB bf16 act

  k_setup<<<2048, 256, 0, stream>>>(x, (unsigned int*)xb, out);
  k_router<<<1, 1024, 0, stream>>>(rp, counts, base, toklist, wlist);
  k_gemm13<<<1024, 512, 0, stream>>>(fc1, fc3, xb, counts, base, toklist, act);
  k_gemm2<<<2048, 512, 0, stream>>>(fc2, act, counts, base, toklist, wlist, out);
}